// Round 2
// baseline (1573.648 us; speedup 1.0000x reference)
//
#include <hip/hip_runtime.h>
#include <hip/hip_bf16.h>

// SL-GAD forward. Inputs/outputs are FLOAT32 (per reference dtypes).
// Output layout: [L, scores(8192)] f32.
#define BB 8192
#define KK 16
#define EE 64
#define FINN 300
#define FOUTN 64

__device__ __forceinline__ float blo(unsigned u) { return __uint_as_float(u << 16); }
__device__ __forceinline__ float bhi(unsigned u) { return __uint_as_float(u & 0xffff0000u); }

// pack two f32 into bf16 pair (round-to-nearest-even)
__device__ __forceinline__ unsigned packbf(float a, float b) {
  unsigned ua = __float_as_uint(a), ub = __float_as_uint(b);
  ua = (ua + 0x7fffu + ((ua >> 16) & 1u)) >> 16;
  ub = (ub + 0x7fffu + ((ub >> 16) & 1u)) >> 16;
  return ua | (ub << 16);
}

__device__ __forceinline__ float waveSum(float v) {
#pragma unroll
  for (int off = 32; off > 0; off >>= 1) v += __shfl_xor(v, off, 64);
  return v;
}

__device__ __forceinline__ float logsig(float z) {  // log(sigmoid(z)), stable
  return fminf(z, 0.f) - log1pf(expf(-fabsf(z)));
}

// ---------------- encoder (fused GEMM + spmm + pool + anchor + decoder-gather) ----
// block = 256 threads = 4 graphs; wave wv owns graph b0+wv in phase 2.
// LDS: feat staging as bf16 pairs (64 rows x 151 dwords = 38656 B, pad dword
// unused) overlaid by agg/dinv/rn after the GEMM barrier; x tile (64x65 f32,
// odd stride -> conflict-free) kept live. Total 55296 B -> 2 blocks/CU.
__global__ __launch_bounds__(256, 2) void enc_kernel(
    const float* __restrict__ feat, const float* __restrict__ wedg,
    const int* __restrict__ src, const int* __restrict__ dst,
    const float* __restrict__ Wenc, const float* __restrict__ benc,
    float* __restrict__ pool_out, float* __restrict__ a_out,
    float* __restrict__ g_out, float* __restrict__ nd0_out)
{
  __shared__ char smem[55296];
  unsigned* featL = (unsigned*)smem;             // 64 rows * 151 dwords (bf16 pairs)
  float* xL = (float*)(smem + 38656);            // 64 * 65 floats
  float* aggL = (float*)smem;                    // overlay: 64 * 65 floats
  float* dinvS = (float*)(smem + 16640);         // 64
  float* rnInv = dinvS + 64;                     // 64

  const int tid = threadIdx.x;
  const int lane = tid & 63;
  const int wv = tid >> 6;
  const int b0 = blockIdx.x * 4;

  // stage feat for 4 graphs: 19200 f32 = 4800 float4, convert -> bf16 pairs
  {
    const float4* __restrict__ gf = (const float4*)(feat + (size_t)b0 * KK * FINN);
    for (int it = tid; it < 4800; it += 256) {
      const float4 v = gf[it];
      const int row = it / 75;            // 75 float4 per 300-float row
      const int c4 = it - row * 75;
      featL[row * 151 + c4 * 2]     = packbf(v.x, v.y);
      featL[row * 151 + c4 * 2 + 1] = packbf(v.z, v.w);
    }
  }
  __syncthreads();

  // GEMM: x[r][j] = sum_i feat[r][i] * Wenc[i][j]; lane=row, wave=16-col chunk.
  const int jc = __builtin_amdgcn_readfirstlane(wv);
  float acc[16];
#pragma unroll
  for (int q = 0; q < 16; ++q) acc[q] = 0.f;
  for (int i2 = 0; i2 < FINN / 2; ++i2) {
    const unsigned fp = featL[lane * 151 + i2];   // 2-way bank alias (free)
    const float f0 = blo(fp), f1 = bhi(fp);
    const float* __restrict__ w0 = Wenc + (2 * i2) * 64 + jc * 16;  // uniform -> s_load
    const float* __restrict__ w1 = w0 + 64;
#pragma unroll
    for (int q = 0; q < 16; ++q)
      acc[q] = fmaf(f1, w1[q], fmaf(f0, w0[q], acc[q]));
  }
#pragma unroll
  for (int q = 0; q < 16; ++q) xL[lane * 65 + jc * 16 + q] = acc[q];
  __syncthreads();

  // -------- phase 2: wave wv handles graph b, lane = feature j (0..63)
  const int j = lane;
  const int bu = __builtin_amdgcn_readfirstlane(b0 + wv);
  const float bias = benc[j];

  if (a_out) {  // anchor_out = l2n(relu(feat0 @ W + b))
    const float a = fmaxf(xL[(wv * 16) * 65 + j] + bias, 0.f);
    const float n2 = waveSum(a * a);
    a_out[(size_t)bu * 64 + j] = a * (1.f / fmaxf(sqrtf(n2), 1e-12f));
  }

  const int* __restrict__ sb = src + bu * EE;
  const int* __restrict__ db = dst + bu * EE;
  const float* __restrict__ wb = wedg + bu * EE;
  {  // degrees via ballot (lane = edge)
    const int myS = sb[j];
    const int myD = db[j];
#pragma unroll
    for (int k = 0; k < 16; ++k) {
      const int cS = __popcll(__ballot(myS == k));
      if (j == 0) dinvS[wv * 16 + k] = rsqrtf(fmaxf((float)cS, 1.f));
    }
    if (nd0_out) {
      const int cD0 = __popcll(__ballot(myD == 0));
      if (j == 0) nd0_out[bu] = rsqrtf(fmaxf((float)cD0, 1.f));
    }
  }

#pragma unroll
  for (int k = 0; k < 16; ++k) aggL[(wv * 16 + k) * 65 + j] = 0.f;
  for (int e = 0; e < EE; ++e) {  // encoder spmm (fz => src 0 contributes nothing)
    const int se = sb[e];
    if (se == 0) continue;
    const int de = db[e];
    const float we = wb[e];
    aggL[(wv * 16 + de) * 65 + j] += we * xL[(wv * 16 + se) * 65 + j];
  }

  float pool = 0.f;
#pragma unroll
  for (int k = 0; k < 16; ++k) {  // h = relu(agg + b); pool = mean_k h
    const float v = fmaxf(aggL[(wv * 16 + k) * 65 + j] + bias, 0.f);
    aggL[(wv * 16 + k) * 65 + j] = v;
    pool += v;
  }
  pool *= (1.f / 16.f);
  {
    const float n2 = waveSum(pool * pool);
    pool_out[(size_t)bu * 64 + j] = pool * (1.f / fmaxf(sqrtf(n2), 1e-12f));
  }

  if (g_out) {  // decoder gather: g = sum_{e:dst=0} w_e * dS(src)^-.5 * h_norm[src]
    if (j < 16) {
      float sq = 0.f;
      for (int q = 0; q < 64; ++q) {
        const float v = aggL[(wv * 16 + j) * 65 + q];
        sq += v * v;
      }
      rnInv[wv * 16 + j] = 1.f / fmaxf(sqrtf(sq), 1e-12f);
    }
    float g = 0.f;
    for (int e = 0; e < EE; ++e) {
      const int de = db[e];
      if (de != 0) continue;
      const int se = sb[e];
      g += wb[e] * dinvS[wv * 16 + se] * rnInv[wv * 16 + se] * aggL[(wv * 16 + se) * 65 + j];
    }
    g_out[(size_t)bu * 64 + j] = g;
  }
}

// ---------------- decoder anchor + loss accumulation (per graph) -----------------
__global__ __launch_bounds__(256) void dec_kernel(
    const float* __restrict__ g_buf, const float* __restrict__ nd0_buf,
    const float* __restrict__ Wdec, const float* __restrict__ bdec,
    const float* __restrict__ feat, double* __restrict__ Tacc)
{
  __shared__ float red[8];
  __shared__ float invn_s;
  const int t = threadIdx.x;
  const int b = blockIdx.x;
  const float* __restrict__ gb = g_buf + (size_t)b * 64;
  const float nd0 = nd0_buf[b];
  const int f0 = t, f1 = t + 256;
  const bool has1 = (f1 < FINN);
  float y0 = 0.f, y1 = 0.f;
  for (int jj = 0; jj < 64; ++jj) {
    const float gj = gb[jj];  // uniform -> s_load
    y0 = fmaf(gj, Wdec[jj * FINN + f0], y0);
    if (has1) y1 = fmaf(gj, Wdec[jj * FINN + f1], y1);
  }
  const float a0 = fmaxf(y0 * nd0 + bdec[f0], 0.f);
  const float a1 = has1 ? fmaxf(y1 * nd0 + bdec[f1], 0.f) : 0.f;
  float ss = waveSum(a0 * a0 + a1 * a1);
  if ((t & 63) == 0) red[t >> 6] = ss;
  __syncthreads();
  if (t == 0) invn_s = 1.f / fmaxf(sqrtf(red[0] + red[1] + red[2] + red[3]), 1e-12f);
  __syncthreads();
  const float inv = invn_s;
  const float* __restrict__ ori = feat + (size_t)b * KK * FINN;  // row 0
  const float d0 = a0 * inv - ori[f0];
  const float d1 = has1 ? (a1 * inv - ori[f1]) : 0.f;
  float sd = waveSum(d0 * d0 + d1 * d1);
  if ((t & 63) == 0) red[4 + (t >> 6)] = sd;
  __syncthreads();
  if (t == 0) atomicAdd(Tacc, (double)(red[4] + red[5] + red[6] + red[7]));
}

// ---------------- bilinear discriminator ----------------------------------------
__global__ __launch_bounds__(256) void bil_kernel(
    const float* __restrict__ pool1, const float* __restrict__ pool2,
    const float* __restrict__ pooln, const float* __restrict__ a1b,
    const float* __restrict__ a2b, const float* __restrict__ Wbil,
    const float* __restrict__ bbil, float* __restrict__ contr,
    double* __restrict__ S1, double* __restrict__ S2)
{
  __shared__ float p1s[4][64], p2s[4][64], pns[4][64];
  const int tid = threadIdx.x;
  const int wv = tid >> 6;
  const int j = tid & 63;
  const int bu = __builtin_amdgcn_readfirstlane(blockIdx.x * 4 + wv);
  p1s[wv][j] = pool1[(size_t)bu * 64 + j];
  p2s[wv][j] = pool2[(size_t)bu * 64 + j];
  pns[wv][j] = pooln[(size_t)bu * 64 + j];
  const float A1 = a1b[(size_t)bu * 64 + j];
  const float A2 = a2b[(size_t)bu * 64 + j];
  float v1 = 0.f, v2 = 0.f, vn = 0.f;
  for (int jj = 0; jj < 64; ++jj) {  // v = Wbil^T * pool  (coalesced W rows)
    const float wr = Wbil[jj * 64 + j];
    v1 = fmaf(p1s[wv][jj], wr, v1);
    v2 = fmaf(p2s[wv][jj], wr, v2);
    vn = fmaf(pns[wv][jj], wr, vn);
  }
  const float d11 = waveSum(v1 * A1);
  const float d22 = waveSum(v2 * A2);
  const float dn1 = waveSum(vn * A1);
  const float dn2 = waveSum(vn * A2);
  if (j == 0) {
    const float bb = bbil[0];
    const float z11 = d11 + bb, z22 = d22 + bb, zn1 = dn1 + bb, zn2 = dn2 + bb;
    const float ps1 = 1.f / (1.f + expf(-z11));
    const float ps2 = 1.f / (1.f + expf(-z22));
    const float ns1 = 1.f / (1.f + expf(-zn1));
    const float ns2 = 1.f / (1.f + expf(-zn2));
    contr[bu] = (ns1 - ps1 + 1.f) * 0.5f + (ns2 - ps2 + 1.f) * 0.5f;
    // log(ps) + log(1-ns) = logsig(z11) + logsig(-zn1)
    const float t1 = logsig(z11) + logsig(-zn1);
    const float t2 = logsig(z22) + logsig(-zn2);
    atomicAdd(S1, (double)t1);
    atomicAdd(S2, (double)t2);
  }
}

__global__ void init_kernel(double* acc) { if (threadIdx.x < 4) acc[threadIdx.x] = 0.0; }

__global__ void fin_kernel(const double* __restrict__ acc, float* __restrict__ genw,
                           float* __restrict__ out)
{
  const double T1 = acc[0], T2 = acc[1], S1d = acc[2], S2d = acc[3];
  const double m1 = S1d / (double)BB, m2 = S2d / (double)BB;
  const double Lcon = -(m1 + m2) * 0.25;
  const double Lgen = (T1 + T2) / (2.0 * (double)BB * (double)FINN);
  const double L = 1.0 * Lcon + 0.6 * Lgen;
  const double gen = (sqrt(T1) + sqrt(T2)) / (2.0 * sqrt((double)FINN));
  out[0] = (float)L;
  genw[0] = (float)gen;
}

__global__ void score_kernel(const float* __restrict__ contr, const float* __restrict__ genw,
                             float* __restrict__ out)
{
  const int i = blockIdx.x * blockDim.x + threadIdx.x;
  if (i < BB) out[1 + i] = fmaf(0.6f, genw[0], contr[i]);
}

extern "C" void kernel_launch(void* const* d_in, const int* in_sizes, int n_in,
                              void* d_out, int out_size, void* d_ws, size_t ws_size,
                              hipStream_t stream)
{
  const float* feat_p1 = (const float*)d_in[0];
  const float* feat_p2 = (const float*)d_in[1];
  const float* feat_n  = (const float*)d_in[2];
  const float* w_p1 = (const float*)d_in[3];
  const float* w_p2 = (const float*)d_in[4];
  const float* w_n  = (const float*)d_in[5];
  const float* W_enc = (const float*)d_in[6];
  const float* b_enc = (const float*)d_in[7];
  const float* W_dec = (const float*)d_in[8];
  const float* b_dec = (const float*)d_in[9];
  const float* W_bil = (const float*)d_in[10];
  const float* b_bil = (const float*)d_in[11];
  const int* src_p1 = (const int*)d_in[12];
  const int* dst_p1 = (const int*)d_in[13];
  const int* src_p2 = (const int*)d_in[14];
  const int* dst_p2 = (const int*)d_in[15];
  const int* src_n  = (const int*)d_in[16];
  const int* dst_n  = (const int*)d_in[17];
  float* out = (float*)d_out;

  double* accs = (double*)d_ws;              // [T1, T2, S1, S2]
  float* fws = (float*)d_ws;
  float* genw = fws + 8;
  float* pool1 = fws + 16;
  float* pool2 = pool1 + (size_t)BB * 64;
  float* pooln = pool2 + (size_t)BB * 64;
  float* a1 = pooln + (size_t)BB * 64;
  float* a2 = a1 + (size_t)BB * 64;
  float* g1 = a2 + (size_t)BB * 64;
  float* g2 = g1 + (size_t)BB * 64;
  float* nd01 = g2 + (size_t)BB * 64;
  float* nd02 = nd01 + BB;
  float* contr = nd02 + BB;

  hipLaunchKernelGGL(init_kernel, dim3(1), dim3(64), 0, stream, accs);
  hipLaunchKernelGGL(enc_kernel, dim3(BB / 4), dim3(256), 0, stream,
                     feat_n, w_n, src_n, dst_n, W_enc, b_enc, pooln,
                     (float*)nullptr, (float*)nullptr, (float*)nullptr);
  hipLaunchKernelGGL(enc_kernel, dim3(BB / 4), dim3(256), 0, stream,
                     feat_p1, w_p1, src_p1, dst_p1, W_enc, b_enc, pool1, a1, g1, nd01);
  hipLaunchKernelGGL(enc_kernel, dim3(BB / 4), dim3(256), 0, stream,
                     feat_p2, w_p2, src_p2, dst_p2, W_enc, b_enc, pool2, a2, g2, nd02);
  hipLaunchKernelGGL(dec_kernel, dim3(BB), dim3(256), 0, stream,
                     g1, nd01, W_dec, b_dec, feat_p1, accs + 0);
  hipLaunchKernelGGL(dec_kernel, dim3(BB), dim3(256), 0, stream,
                     g2, nd02, W_dec, b_dec, feat_p2, accs + 1);
  hipLaunchKernelGGL(bil_kernel, dim3(BB / 4), dim3(256), 0, stream,
                     pool1, pool2, pooln, a1, a2, W_bil, b_bil, contr, accs + 2, accs + 3);
  hipLaunchKernelGGL(fin_kernel, dim3(1), dim3(1), 0, stream, accs, genw, out);
  hipLaunchKernelGGL(score_kernel, dim3((BB + 255) / 256), dim3(256), 0, stream,
                     contr, genw, out);
}

// Round 3
// 964.734 us; speedup vs baseline: 1.6312x; 1.6312x over previous
//
#include <hip/hip_runtime.h>

// SL-GAD forward, MFMA version. Inputs/outputs FLOAT32. Output: [L, scores(8192)].
#define BB 8192
#define KK 16
#define EE 64
#define FINN 300

typedef __attribute__((ext_vector_type(8))) short short8;
typedef __attribute__((ext_vector_type(4))) float f32x4;

__device__ __forceinline__ unsigned packbf(float a, float b) {  // 2xf32 -> bf16 pair (RNE)
  unsigned ua = __float_as_uint(a), ub = __float_as_uint(b);
  ua = (ua + 0x7fffu + ((ua >> 16) & 1u)) >> 16;
  ub = (ub + 0x7fffu + ((ub >> 16) & 1u)) >> 16;
  return ua | (ub << 16);
}
__device__ __forceinline__ float redC(float v) {  // sum over lane bits 0..3 (col group)
  v += __shfl_xor(v, 1); v += __shfl_xor(v, 2);
  v += __shfl_xor(v, 4); v += __shfl_xor(v, 8);
  return v;
}
__device__ __forceinline__ float redQ(float v) {  // sum over quads (lane bits 4,5)
  v += __shfl_xor(v, 16); v += __shfl_xor(v, 32);
  return v;
}
__device__ __forceinline__ float waveSum(float v) {
#pragma unroll
  for (int off = 32; off; off >>= 1) v += __shfl_xor(v, off);
  return v;
}
__device__ __forceinline__ float logsig(float z) {  // log(sigmoid(z)), stable
  return fminf(z, 0.f) - log1pf(expf(-fabsf(z)));
}

// prep: W_enc (300x64 f32) -> bf16 B-fragment layout [nt(4)][kstep(10)][lane(64)]x16B
__global__ void prep_kernel(const float* __restrict__ Wenc, uint4* __restrict__ wB) {
  const int id = blockIdx.x * 256 + threadIdx.x;
  if (id >= 2560) return;
  const int lane = id & 63;
  const int step = (id >> 6) % 10;
  const int nt = id / 640;
  const int n = nt * 16 + (lane & 15);
  const int kb = step * 32 + (lane >> 4) * 8;   // B[k=kb+j][n], j=0..7 per lane
  float f[8];
#pragma unroll
  for (int j2 = 0; j2 < 8; ++j2) {
    const int k = kb + j2;
    f[j2] = (k < FINN) ? Wenc[k * 64 + n] : 0.f;
  }
  uint4 o;
  o.x = packbf(f[0], f[1]); o.y = packbf(f[2], f[3]);
  o.z = packbf(f[4], f[5]); o.w = packbf(f[6], f[7]);
  wB[id] = o;
}

// ---------------- encoder: MFMA GEMM + MFMA spmm + pool/anchor/gather ------------
// block = 256 = 4 waves; GEMM: wave = 16-col n-tile over 64 rows; phase2: wave = graph.
// LDS 41984 B -> 3 blocks/CU.
__global__ __launch_bounds__(256, 3) void enc_kernel(
    const float* __restrict__ feat, const float* __restrict__ wedg,
    const int* __restrict__ src, const int* __restrict__ dst,
    const uint4* __restrict__ wB, const float* __restrict__ benc,
    float* __restrict__ pool_out, float* __restrict__ a_out,
    float* __restrict__ g_out, float* __restrict__ nd0_out)
{
  __shared__ char smem[41984];
  // phase 1: feat as bf16, 64 rows x 328 bf16 (656 B rows; cols 300..319 zero)
  unsigned* featU = (unsigned*)smem;        // row*164 + dw
  // phase 2 overlay:
  char* xBc = smem;                         // 16384 B: x bf16 B-frags [g][nt][lane]x16B
  float* AdjL = (float*)(smem + 16384);     // 4 x 256 f32 (dense adjacency, atomic build)
  char* AdjBc = smem + 20480;               // 4 x 16rows x 64B (bf16, s-padded to 32)
  float* coefL = (float*)(smem + 24576);    // 4 x 16 (Adj[0][s] * dinv[s])
  float* xAnch = (float*)(smem + 24832);    // 4 x 64 (x row 0 per graph, f32)

  const int tid = threadIdx.x, lane = tid & 63, wv = tid >> 6;
  const int q = lane >> 4, c = lane & 15;
  const int b0 = blockIdx.x * 4;

  // W B-frags for this wave's n-tile, held in VGPRs (L2-resident, no in-loop chain)
  uint4 bfr[10];
  {
    const uint4* p = wB + (wv * 10) * 64 + lane;
#pragma unroll
    for (int s = 0; s < 10; ++s) bfr[s] = p[s * 64];
  }
  // stage feat (76.8 KB f32 -> bf16 LDS), coalesced float4
  {
    const float4* gf = (const float4*)(feat + (size_t)b0 * (KK * FINN));
    for (int it = tid; it < 4800; it += 256) {
      const float4 v = gf[it];
      const int row = it / 75, c4 = it - row * 75;
      unsigned* p = featU + row * 164 + c4 * 2;
      p[0] = packbf(v.x, v.y);
      p[1] = packbf(v.z, v.w);
    }
    for (int it = tid; it < 896; it += 256)   // zero K-pad cols 300..327
      featU[(it / 14) * 164 + 150 + (it % 14)] = 0;
  }
  __syncthreads();

  // GEMM: acc[m] = feat[m-tile] @ Wenc[:, wv-tile]
  f32x4 acc[4];
#pragma unroll
  for (int m = 0; m < 4; ++m) acc[m] = (f32x4){0.f, 0.f, 0.f, 0.f};
#pragma unroll
  for (int s = 0; s < 10; ++s) {
    const short8 b8 = *(const short8*)&bfr[s];
#pragma unroll
    for (int m = 0; m < 4; ++m) {
      // A-frag: A[mrow=lane&15][k=q*8+j]; row stride 656B = 41x16B (conflict-free b128)
      const short8 a8 = *(const short8*)(smem + (m * 16 + c) * 656 + s * 64 + q * 16);
      acc[m] = __builtin_amdgcn_mfma_f32_16x16x32_bf16(a8, b8, acc[m], 0, 0, 0);
    }
  }
  __syncthreads();  // all featA reads done before overlay writes

  // epilogue: x -> bf16 B-frag layout for the spmm MFMA; x row0 f32 for anchor
#pragma unroll
  for (int m = 0; m < 4; ++m) {
    // C layout: col=lane&15 (in n-tile wv), row=q*4+r (in m-tile m); s=4q+r -> lane'=(q>>1)*16+c, jj=4(q&1)+r
    unsigned* dp = (unsigned*)(xBc + ((m * 4 + wv) * 64 + (q >> 1) * 16 + c) * 16 + (q & 1) * 8);
    dp[0] = packbf(acc[m][0], acc[m][1]);
    dp[1] = packbf(acc[m][2], acc[m][3]);
    if (q == 0) xAnch[m * 64 + wv * 16 + c] = acc[m][0];  // row 4*0+0 = node 0
  }
  {
    const uint4 z = {0, 0, 0, 0};
    for (int i = tid; i < 512; i += 256)            // zero xB K-pad lanes 32..63
      ((uint4*)xBc)[(i >> 5) * 64 + 32 + (i & 31)] = z;
    for (int i = tid; i < 512; i += 256)            // zero AdjL (4KB) + AdjB (4KB)
      ((uint4*)(smem + 16384))[i] = z;
  }
  __syncthreads();

  // -------- phase 2: wave = graph g = wv, lane = edge then (quad,col) roles ------
  const int g = wv;
  const int bu = b0 + wv;
  const int se = src[bu * EE + lane];
  const int de = dst[bu * EE + lane];
  const float we = wedg[bu * EE + lane];

  float dinv_reg = 0.f;  // lane k<16 ends holding dinv_src[k]
#pragma unroll
  for (int k = 0; k < KK; ++k) {
    const int cnt = __popcll(__ballot(se == k));
    if (lane == k) dinv_reg = rsqrtf(fmaxf((float)cnt, 1.f));
  }
  if (nd0_out) {
    const int cd0 = __popcll(__ballot(de == 0));
    if (lane == 0) nd0_out[bu] = rsqrtf(fmaxf((float)cd0, 1.f));
  }
  atomicAdd(&AdjL[g * 256 + de * 16 + se], we);  // dense adjacency build (ds_add)
  __threadfence_block();
  {
    // AdjL -> AdjB bf16 (A-frag rows, s-dim padded to 32 with zeros).
    // Encoder spmm must treat x[0]=0 (fz): zero column s=0 in AdjB only.
    const f32x4 v = *(const f32x4*)(AdjL + g * 256 + lane * 4);
    const float v0 = ((lane & 3) == 0) ? 0.f : v[0];
    unsigned* w = (unsigned*)(AdjBc + g * 1024 + (lane >> 2) * 64 + (lane & 3) * 8);
    w[0] = packbf(v0, v[1]);
    w[1] = packbf(v[2], v[3]);
  }
  if (g_out && lane < KK)  // coef[s] = Adj[0][s] * dinv_src[s] (raw Adj row 0)
    coefL[g * 16 + lane] = AdjL[g * 256 + lane] * dinv_reg;
  __threadfence_block();

  // spmm: agg(16x64) = Adj(16x16,pad32) @ x(16x64,pad32) as 4 MFMA
  const short8 aAdj = *(const short8*)(AdjBc + g * 1024 + c * 64 + q * 16);
  float bj[4], h[4][4];
#pragma unroll
  for (int nt = 0; nt < 4; ++nt) bj[nt] = benc[nt * 16 + c];
#pragma unroll
  for (int nt = 0; nt < 4; ++nt) {
    const short8 xb = *(const short8*)(xBc + ((g * 4 + nt) * 64 + lane) * 16);
    f32x4 cc = (f32x4){0.f, 0.f, 0.f, 0.f};
    cc = __builtin_amdgcn_mfma_f32_16x16x32_bf16(aAdj, xb, cc, 0, 0, 0);
#pragma unroll
    for (int r = 0; r < 4; ++r) h[nt][r] = fmaxf(cc[r] + bj[nt], 0.f);  // node 4q+r, col nt*16+c
  }

  // pool = l2n(sum_k h) (mean's 1/16 cancels in l2n)
  float pl[4];
#pragma unroll
  for (int nt = 0; nt < 4; ++nt)
    pl[nt] = redQ(h[nt][0] + h[nt][1] + h[nt][2] + h[nt][3]);
  float pn2 = redC(pl[0] * pl[0] + pl[1] * pl[1] + pl[2] * pl[2] + pl[3] * pl[3]);
  const float pinv = 1.f / fmaxf(sqrtf(pn2), 1e-12f);
  if (q == 0)
#pragma unroll
    for (int nt = 0; nt < 4; ++nt)
      pool_out[(size_t)bu * 64 + nt * 16 + c] = pl[nt] * pinv;

  if (g_out) {  // gather: g[j] = sum_s coef[s] * l2n(h)[s][j]
    float rnv[4];
#pragma unroll
    for (int r = 0; r < 4; ++r) {
      float s2 = redC(h[0][r] * h[0][r] + h[1][r] * h[1][r] +
                      h[2][r] * h[2][r] + h[3][r] * h[3][r]);
      rnv[r] = 1.f / fmaxf(sqrtf(s2), 1e-12f);
    }
    float gp[4] = {0.f, 0.f, 0.f, 0.f};
#pragma unroll
    for (int r = 0; r < 4; ++r) {
      const float cf = coefL[g * 16 + q * 4 + r] * rnv[r];
#pragma unroll
      for (int nt = 0; nt < 4; ++nt) gp[nt] = fmaf(cf, h[nt][r], gp[nt]);
    }
#pragma unroll
    for (int nt = 0; nt < 4; ++nt) gp[nt] = redQ(gp[nt]);
    if (q == 1)
#pragma unroll
      for (int nt = 0; nt < 4; ++nt)
        g_out[(size_t)bu * 64 + nt * 16 + c] = gp[nt];
  }
  if (a_out) {  // anchor = l2n(relu(x[0] + b))
    float av[4], an2 = 0.f;
#pragma unroll
    for (int nt = 0; nt < 4; ++nt) {
      av[nt] = fmaxf(xAnch[g * 64 + nt * 16 + c] + bj[nt], 0.f);
      an2 += av[nt] * av[nt];
    }
    an2 = redC(an2);
    const float ainv = 1.f / fmaxf(sqrtf(an2), 1e-12f);
    if (q == 2)
#pragma unroll
      for (int nt = 0; nt < 4; ++nt)
        a_out[(size_t)bu * 64 + nt * 16 + c] = av[nt] * ainv;
  }
}

// ---------------- decoder anchor + loss accumulation (per graph) -----------------
__global__ __launch_bounds__(256) void dec_kernel(
    const float* __restrict__ g_buf, const float* __restrict__ nd0_buf,
    const float* __restrict__ Wdec, const float* __restrict__ bdec,
    const float* __restrict__ feat, double* __restrict__ Tacc)
{
  __shared__ float red[8];
  __shared__ float invn_s;
  const int t = threadIdx.x, b = blockIdx.x;
  const float gv = g_buf[(size_t)b * 64 + (t & 63)];  // g held across wave, shfl-broadcast
  const float nd0 = nd0_buf[b];
  const int f0 = t, f1 = t + 256;
  const bool has1 = (f1 < FINN);
  float y0 = 0.f, y1 = 0.f;
  for (int jj = 0; jj < 64; ++jj) {
    const float gj = __shfl(gv, jj);
    y0 = fmaf(gj, Wdec[jj * FINN + f0], y0);
    if (has1) y1 = fmaf(gj, Wdec[jj * FINN + f1], y1);
  }
  const float a0 = fmaxf(y0 * nd0 + bdec[f0], 0.f);
  const float a1 = has1 ? fmaxf(y1 * nd0 + bdec[f1], 0.f) : 0.f;
  float ss = waveSum(a0 * a0 + a1 * a1);
  if ((t & 63) == 0) red[t >> 6] = ss;
  __syncthreads();
  if (t == 0) invn_s = 1.f / fmaxf(sqrtf(red[0] + red[1] + red[2] + red[3]), 1e-12f);
  __syncthreads();
  const float inv = invn_s;
  const float* __restrict__ ori = feat + (size_t)b * KK * FINN;  // row 0
  const float d0 = a0 * inv - ori[f0];
  const float d1 = has1 ? (a1 * inv - ori[f1]) : 0.f;
  float sd = waveSum(d0 * d0 + d1 * d1);
  if ((t & 63) == 0) red[4 + (t >> 6)] = sd;
  __syncthreads();
  if (t == 0) atomicAdd(Tacc, (double)(red[4] + red[5] + red[6] + red[7]));
}

// ---------------- bilinear discriminator ----------------------------------------
__global__ __launch_bounds__(256) void bil_kernel(
    const float* __restrict__ pool1, const float* __restrict__ pool2,
    const float* __restrict__ pooln, const float* __restrict__ a1b,
    const float* __restrict__ a2b, const float* __restrict__ Wbil,
    const float* __restrict__ bbil, float* __restrict__ contr,
    double* __restrict__ S1, double* __restrict__ S2)
{
  const int tid = threadIdx.x, wv = tid >> 6, j = tid & 63;
  const int bu = blockIdx.x * 4 + wv;
  const float p1 = pool1[(size_t)bu * 64 + j];
  const float p2 = pool2[(size_t)bu * 64 + j];
  const float pn = pooln[(size_t)bu * 64 + j];
  const float A1 = a1b[(size_t)bu * 64 + j];
  const float A2 = a2b[(size_t)bu * 64 + j];
  float v1 = 0.f, v2 = 0.f, vn = 0.f;
  for (int jj = 0; jj < 64; ++jj) {
    const float wr = Wbil[jj * 64 + j];  // coalesced row
    v1 = fmaf(__shfl(p1, jj), wr, v1);
    v2 = fmaf(__shfl(p2, jj), wr, v2);
    vn = fmaf(__shfl(pn, jj), wr, vn);
  }
  const float d11 = waveSum(v1 * A1);
  const float d22 = waveSum(v2 * A2);
  const float dn1 = waveSum(vn * A1);
  const float dn2 = waveSum(vn * A2);
  if (j == 0) {
    const float bb = bbil[0];
    const float z11 = d11 + bb, z22 = d22 + bb, zn1 = dn1 + bb, zn2 = dn2 + bb;
    const float ps1 = 1.f / (1.f + expf(-z11));
    const float ps2 = 1.f / (1.f + expf(-z22));
    const float ns1 = 1.f / (1.f + expf(-zn1));
    const float ns2 = 1.f / (1.f + expf(-zn2));
    contr[bu] = (ns1 - ps1 + 1.f) * 0.5f + (ns2 - ps2 + 1.f) * 0.5f;
    const float t1 = logsig(z11) + logsig(-zn1);
    const float t2 = logsig(z22) + logsig(-zn2);
    atomicAdd(S1, (double)t1);
    atomicAdd(S2, (double)t2);
  }
}

__global__ void init_kernel(double* acc) { if (threadIdx.x < 4) acc[threadIdx.x] = 0.0; }

__global__ void fin_kernel(const double* __restrict__ acc, float* __restrict__ genw,
                           float* __restrict__ out)
{
  const double T1 = acc[0], T2 = acc[1], S1d = acc[2], S2d = acc[3];
  const double m1 = S1d / (double)BB, m2 = S2d / (double)BB;
  const double Lcon = -(m1 + m2) * 0.25;
  const double Lgen = (T1 + T2) / (2.0 * (double)BB * (double)FINN);
  out[0] = (float)(Lcon + 0.6 * Lgen);
  genw[0] = (float)((sqrt(T1) + sqrt(T2)) / (2.0 * sqrt((double)FINN)));
}

__global__ void score_kernel(const float* __restrict__ contr, const float* __restrict__ genw,
                             float* __restrict__ out)
{
  const int i = blockIdx.x * blockDim.x + threadIdx.x;
  if (i < BB) out[1 + i] = fmaf(0.6f, genw[0], contr[i]);
}

extern "C" void kernel_launch(void* const* d_in, const int* in_sizes, int n_in,
                              void* d_out, int out_size, void* d_ws, size_t ws_size,
                              hipStream_t stream)
{
  const float* feat_p1 = (const float*)d_in[0];
  const float* feat_p2 = (const float*)d_in[1];
  const float* feat_n  = (const float*)d_in[2];
  const float* w_p1 = (const float*)d_in[3];
  const float* w_p2 = (const float*)d_in[4];
  const float* w_n  = (const float*)d_in[5];
  const float* W_enc = (const float*)d_in[6];
  const float* b_enc = (const float*)d_in[7];
  const float* W_dec = (const float*)d_in[8];
  const float* b_dec = (const float*)d_in[9];
  const float* W_bil = (const float*)d_in[10];
  const float* b_bil = (const float*)d_in[11];
  const int* src_p1 = (const int*)d_in[12];
  const int* dst_p1 = (const int*)d_in[13];
  const int* src_p2 = (const int*)d_in[14];
  const int* dst_p2 = (const int*)d_in[15];
  const int* src_n  = (const int*)d_in[16];
  const int* dst_n  = (const int*)d_in[17];
  float* out = (float*)d_out;

  double* accs = (double*)d_ws;                          // [T1,T2,S1,S2]
  float* genw = (float*)((char*)d_ws + 32);
  uint4* wsB = (uint4*)((char*)d_ws + 1024);             // 40960 B W_enc frags
  float* fws = (float*)((char*)d_ws + 49152);
  float* pool1 = fws;
  float* pool2 = pool1 + (size_t)BB * 64;
  float* pooln = pool2 + (size_t)BB * 64;
  float* a1 = pooln + (size_t)BB * 64;
  float* a2 = a1 + (size_t)BB * 64;
  float* g1 = a2 + (size_t)BB * 64;
  float* g2 = g1 + (size_t)BB * 64;
  float* nd01 = g2 + (size_t)BB * 64;
  float* nd02 = nd01 + BB;
  float* contr = nd02 + BB;

  hipLaunchKernelGGL(init_kernel, dim3(1), dim3(64), 0, stream, accs);
  hipLaunchKernelGGL(prep_kernel, dim3(10), dim3(256), 0, stream, W_enc, wsB);
  hipLaunchKernelGGL(enc_kernel, dim3(BB / 4), dim3(256), 0, stream,
                     feat_n, w_n, src_n, dst_n, wsB, b_enc, pooln,
                     (float*)nullptr, (float*)nullptr, (float*)nullptr);
  hipLaunchKernelGGL(enc_kernel, dim3(BB / 4), dim3(256), 0, stream,
                     feat_p1, w_p1, src_p1, dst_p1, wsB, b_enc, pool1, a1, g1, nd01);
  hipLaunchKernelGGL(enc_kernel, dim3(BB / 4), dim3(256), 0, stream,
                     feat_p2, w_p2, src_p2, dst_p2, wsB, b_enc, pool2, a2, g2, nd02);
  hipLaunchKernelGGL(dec_kernel, dim3(BB), dim3(256), 0, stream,
                     g1, nd01, W_dec, b_dec, feat_p1, accs + 0);
  hipLaunchKernelGGL(dec_kernel, dim3(BB), dim3(256), 0, stream,
                     g2, nd02, W_dec, b_dec, feat_p2, accs + 1);
  hipLaunchKernelGGL(bil_kernel, dim3(BB / 4), dim3(256), 0, stream,
                     pool1, pool2, pooln, a1, a2, W_bil, b_bil, contr, accs + 2, accs + 3);
  hipLaunchKernelGGL(fin_kernel, dim3(1), dim3(1), 0, stream, accs, genw, out);
  hipLaunchKernelGGL(score_kernel, dim3((BB + 255) / 256), dim3(256), 0, stream,
                     contr, genw, out);
}

// Round 4
// 654.675 us; speedup vs baseline: 2.4037x; 1.4736x over previous
//
#include <hip/hip_runtime.h>

// SL-GAD forward, MFMA version. Inputs/outputs FLOAT32. Output: [L, scores(8192)].
#define BB 8192
#define KK 16
#define EE 64
#define FINN 300

typedef __attribute__((ext_vector_type(8))) short short8;
typedef __attribute__((ext_vector_type(4))) float f32x4;

__device__ __forceinline__ unsigned packbf(float a, float b) {  // 2xf32 -> bf16 pair (RNE)
  unsigned ua = __float_as_uint(a), ub = __float_as_uint(b);
  ua = (ua + 0x7fffu + ((ua >> 16) & 1u)) >> 16;
  ub = (ub + 0x7fffu + ((ub >> 16) & 1u)) >> 16;
  return ua | (ub << 16);
}
__device__ __forceinline__ float redC(float v) {  // sum over lane bits 0..3 (col group)
  v += __shfl_xor(v, 1); v += __shfl_xor(v, 2);
  v += __shfl_xor(v, 4); v += __shfl_xor(v, 8);
  return v;
}
__device__ __forceinline__ float redQ(float v) {  // sum over quads (lane bits 4,5)
  v += __shfl_xor(v, 16); v += __shfl_xor(v, 32);
  return v;
}
__device__ __forceinline__ float waveSum(float v) {
#pragma unroll
  for (int off = 32; off; off >>= 1) v += __shfl_xor(v, off);
  return v;
}
__device__ __forceinline__ float logsig(float z) {  // log(sigmoid(z)), stable
  return fminf(z, 0.f) - log1pf(expf(-fabsf(z)));
}

// prep: W_enc (300x64 f32) -> bf16 B-fragment layout [nt(4)][kstep(10)][lane(64)]x16B
__global__ void prep_kernel(const float* __restrict__ Wenc, uint4* __restrict__ wB) {
  const int id = blockIdx.x * 256 + threadIdx.x;
  if (id >= 2560) return;
  const int lane = id & 63;
  const int step = (id >> 6) % 10;
  const int nt = id / 640;
  const int n = nt * 16 + (lane & 15);
  const int kb = step * 32 + (lane >> 4) * 8;   // B[k=kb+j][n], j=0..7 per lane
  float f[8];
#pragma unroll
  for (int j2 = 0; j2 < 8; ++j2) {
    const int k = kb + j2;
    f[j2] = (k < FINN) ? Wenc[k * 64 + n] : 0.f;
  }
  uint4 o;
  o.x = packbf(f[0], f[1]); o.y = packbf(f[2], f[3]);
  o.z = packbf(f[4], f[5]); o.w = packbf(f[6], f[7]);
  wB[id] = o;
}

// ---------------- encoder: MFMA GEMM + MFMA spmm + pool/anchor/gather ------------
// block = 256 = 4 waves; GEMM: wave = 16-col n-tile over 64 rows; phase2: wave = graph.
// LDS 41984 B -> 3 blocks/CU.
__global__ __launch_bounds__(256, 3) void enc_kernel(
    const float* __restrict__ feat, const float* __restrict__ wedg,
    const int* __restrict__ src, const int* __restrict__ dst,
    const uint4* __restrict__ wB, const float* __restrict__ benc,
    float* __restrict__ pool_out, float* __restrict__ a_out,
    float* __restrict__ g_out, float* __restrict__ nd0_out)
{
  __shared__ char smem[41984];
  // phase 1: feat as bf16, 64 rows x 328 bf16 (656 B rows; cols 300..319 zero)
  unsigned* featU = (unsigned*)smem;        // row*164 + dw
  // phase 2 overlay:
  char* xBc = smem;                         // 16384 B: x bf16 B-frags [g][nt][lane]x16B
  float* AdjL = (float*)(smem + 16384);     // 4 x 256 f32 (dense adjacency, atomic build)
  char* AdjBc = smem + 20480;               // 4 x 16rows x 64B (bf16, s-padded to 32)
  float* coefL = (float*)(smem + 24576);    // 4 x 16 (Adj[0][s] * dinv[s])
  float* xAnch = (float*)(smem + 24832);    // 4 x 64 (x row 0 per graph, f32)

  const int tid = threadIdx.x, lane = tid & 63, wv = tid >> 6;
  const int q = lane >> 4, c = lane & 15;
  const int b0 = blockIdx.x * 4;

  // W B-frags for this wave's n-tile, held in VGPRs (L2-resident, no in-loop chain)
  uint4 bfr[10];
  {
    const uint4* p = wB + (wv * 10) * 64 + lane;
#pragma unroll
    for (int s = 0; s < 10; ++s) bfr[s] = p[s * 64];
  }
  // stage feat (76.8 KB f32 -> bf16 LDS), coalesced float4
  {
    const float4* gf = (const float4*)(feat + (size_t)b0 * (KK * FINN));
    for (int it = tid; it < 4800; it += 256) {
      const float4 v = gf[it];
      const int row = it / 75, c4 = it - row * 75;
      unsigned* p = featU + row * 164 + c4 * 2;
      p[0] = packbf(v.x, v.y);
      p[1] = packbf(v.z, v.w);
    }
    for (int it = tid; it < 896; it += 256)   // zero K-pad cols 300..327
      featU[(it / 14) * 164 + 150 + (it % 14)] = 0;
  }
  __syncthreads();

  // GEMM: acc[m] = feat[m-tile] @ Wenc[:, wv-tile]
  f32x4 acc[4];
#pragma unroll
  for (int m = 0; m < 4; ++m) acc[m] = (f32x4){0.f, 0.f, 0.f, 0.f};
#pragma unroll
  for (int s = 0; s < 10; ++s) {
    const short8 b8 = *(const short8*)&bfr[s];
#pragma unroll
    for (int m = 0; m < 4; ++m) {
      // A-frag: A[mrow=lane&15][k=q*8+j]; row stride 656B = 41x16B (conflict-free b128)
      const short8 a8 = *(const short8*)(smem + (m * 16 + c) * 656 + s * 64 + q * 16);
      acc[m] = __builtin_amdgcn_mfma_f32_16x16x32_bf16(a8, b8, acc[m], 0, 0, 0);
    }
  }
  __syncthreads();  // all featA reads done before overlay writes

  // epilogue: x -> bf16 B-frag layout for the spmm MFMA; x row0 f32 for anchor
#pragma unroll
  for (int m = 0; m < 4; ++m) {
    // C layout: col=lane&15 (in n-tile wv), row=q*4+r (in m-tile m); s=4q+r -> lane'=(q>>1)*16+c, jj=4(q&1)+r
    unsigned* dp = (unsigned*)(xBc + ((m * 4 + wv) * 64 + (q >> 1) * 16 + c) * 16 + (q & 1) * 8);
    dp[0] = packbf(acc[m][0], acc[m][1]);
    dp[1] = packbf(acc[m][2], acc[m][3]);
    if (q == 0) xAnch[m * 64 + wv * 16 + c] = acc[m][0];  // row 4*0+0 = node 0
  }
  {
    const uint4 z = {0, 0, 0, 0};
    for (int i = tid; i < 512; i += 256)            // zero xB K-pad lanes 32..63
      ((uint4*)xBc)[(i >> 5) * 64 + 32 + (i & 31)] = z;
    for (int i = tid; i < 512; i += 256)            // zero AdjL (4KB) + AdjB (4KB)
      ((uint4*)(smem + 16384))[i] = z;
  }
  __syncthreads();

  // -------- phase 2: wave = graph g = wv, lane = edge then (quad,col) roles ------
  const int g = wv;
  const int bu = b0 + wv;
  const int se = src[bu * EE + lane];
  const int de = dst[bu * EE + lane];
  const float we = wedg[bu * EE + lane];

  float dinv_reg = 0.f;  // lane k<16 ends holding dinv_src[k]
#pragma unroll
  for (int k = 0; k < KK; ++k) {
    const int cnt = __popcll(__ballot(se == k));
    if (lane == k) dinv_reg = rsqrtf(fmaxf((float)cnt, 1.f));
  }
  if (nd0_out) {
    const int cd0 = __popcll(__ballot(de == 0));
    if (lane == 0) nd0_out[bu] = rsqrtf(fmaxf((float)cd0, 1.f));
  }
  atomicAdd(&AdjL[g * 256 + de * 16 + se], we);  // dense adjacency build (ds_add, block-local)
  __threadfence_block();
  {
    // AdjL -> AdjB bf16 (A-frag rows, s-dim padded to 32 with zeros).
    // Encoder spmm must treat x[0]=0 (fz): zero column s=0 in AdjB only.
    const f32x4 v = *(const f32x4*)(AdjL + g * 256 + lane * 4);
    const float v0 = ((lane & 3) == 0) ? 0.f : v[0];
    unsigned* w = (unsigned*)(AdjBc + g * 1024 + (lane >> 2) * 64 + (lane & 3) * 8);
    w[0] = packbf(v0, v[1]);
    w[1] = packbf(v[2], v[3]);
  }
  if (g_out && lane < KK)  // coef[s] = Adj[0][s] * dinv_src[s] (raw Adj row 0)
    coefL[g * 16 + lane] = AdjL[g * 256 + lane] * dinv_reg;
  __threadfence_block();

  // spmm: agg(16x64) = Adj(16x16,pad32) @ x(16x64,pad32) as 4 MFMA
  const short8 aAdj = *(const short8*)(AdjBc + g * 1024 + c * 64 + q * 16);
  float bj[4], h[4][4];
#pragma unroll
  for (int nt = 0; nt < 4; ++nt) bj[nt] = benc[nt * 16 + c];
#pragma unroll
  for (int nt = 0; nt < 4; ++nt) {
    const short8 xb = *(const short8*)(xBc + ((g * 4 + nt) * 64 + lane) * 16);
    f32x4 cc = (f32x4){0.f, 0.f, 0.f, 0.f};
    cc = __builtin_amdgcn_mfma_f32_16x16x32_bf16(aAdj, xb, cc, 0, 0, 0);
#pragma unroll
    for (int r = 0; r < 4; ++r) h[nt][r] = fmaxf(cc[r] + bj[nt], 0.f);  // node 4q+r, col nt*16+c
  }

  // pool = l2n(sum_k h) (mean's 1/16 cancels in l2n)
  float pl[4];
#pragma unroll
  for (int nt = 0; nt < 4; ++nt)
    pl[nt] = redQ(h[nt][0] + h[nt][1] + h[nt][2] + h[nt][3]);
  float pn2 = redC(pl[0] * pl[0] + pl[1] * pl[1] + pl[2] * pl[2] + pl[3] * pl[3]);
  const float pinv = 1.f / fmaxf(sqrtf(pn2), 1e-12f);
  if (q == 0)
#pragma unroll
    for (int nt = 0; nt < 4; ++nt)
      pool_out[(size_t)bu * 64 + nt * 16 + c] = pl[nt] * pinv;

  if (g_out) {  // gather: g[j] = sum_s coef[s] * l2n(h)[s][j]
    float rnv[4];
#pragma unroll
    for (int r = 0; r < 4; ++r) {
      float s2 = redC(h[0][r] * h[0][r] + h[1][r] * h[1][r] +
                      h[2][r] * h[2][r] + h[3][r] * h[3][r]);
      rnv[r] = 1.f / fmaxf(sqrtf(s2), 1e-12f);
    }
    float gp[4] = {0.f, 0.f, 0.f, 0.f};
#pragma unroll
    for (int r = 0; r < 4; ++r) {
      const float cf = coefL[g * 16 + q * 4 + r] * rnv[r];
#pragma unroll
      for (int nt = 0; nt < 4; ++nt) gp[nt] = fmaf(cf, h[nt][r], gp[nt]);
    }
#pragma unroll
    for (int nt = 0; nt < 4; ++nt) gp[nt] = redQ(gp[nt]);
    if (q == 1)
#pragma unroll
      for (int nt = 0; nt < 4; ++nt)
        g_out[(size_t)bu * 64 + nt * 16 + c] = gp[nt];
  }
  if (a_out) {  // anchor = l2n(relu(x[0] + b))
    float av[4], an2 = 0.f;
#pragma unroll
    for (int nt = 0; nt < 4; ++nt) {
      av[nt] = fmaxf(xAnch[g * 64 + nt * 16 + c] + bj[nt], 0.f);
      an2 += av[nt] * av[nt];
    }
    an2 = redC(an2);
    const float ainv = 1.f / fmaxf(sqrtf(an2), 1e-12f);
    if (q == 2)
#pragma unroll
      for (int nt = 0; nt < 4; ++nt)
        a_out[(size_t)bu * 64 + nt * 16 + c] = av[nt] * ainv;
  }
}

// ---------------- decoder anchor + per-graph loss term (NO global atomics) -------
__global__ __launch_bounds__(256) void dec_kernel(
    const float* __restrict__ g_buf, const float* __restrict__ nd0_buf,
    const float* __restrict__ Wdec, const float* __restrict__ bdec,
    const float* __restrict__ feat, float* __restrict__ dArr)
{
  __shared__ float red[8];
  __shared__ float invn_s;
  const int t = threadIdx.x, b = blockIdx.x;
  const float gv = g_buf[(size_t)b * 64 + (t & 63)];  // g held across wave, shfl-broadcast
  const float nd0 = nd0_buf[b];
  const int f0 = t, f1 = t + 256;
  const bool has1 = (f1 < FINN);
  float y0 = 0.f, y1 = 0.f;
  for (int jj = 0; jj < 64; ++jj) {
    const float gj = __shfl(gv, jj);
    y0 = fmaf(gj, Wdec[jj * FINN + f0], y0);
    if (has1) y1 = fmaf(gj, Wdec[jj * FINN + f1], y1);
  }
  const float a0 = fmaxf(y0 * nd0 + bdec[f0], 0.f);
  const float a1 = has1 ? fmaxf(y1 * nd0 + bdec[f1], 0.f) : 0.f;
  float ss = waveSum(a0 * a0 + a1 * a1);
  if ((t & 63) == 0) red[t >> 6] = ss;
  __syncthreads();
  if (t == 0) invn_s = 1.f / fmaxf(sqrtf(red[0] + red[1] + red[2] + red[3]), 1e-12f);
  __syncthreads();
  const float inv = invn_s;
  const float* __restrict__ ori = feat + (size_t)b * KK * FINN;  // row 0
  const float d0 = a0 * inv - ori[f0];
  const float d1 = has1 ? (a1 * inv - ori[f1]) : 0.f;
  float sd = waveSum(d0 * d0 + d1 * d1);
  if ((t & 63) == 0) red[4 + (t >> 6)] = sd;
  __syncthreads();
  if (t == 0) dArr[b] = red[4] + red[5] + red[6] + red[7];
}

// ---------------- bilinear discriminator (NO global atomics) ---------------------
__global__ __launch_bounds__(256) void bil_kernel(
    const float* __restrict__ pool1, const float* __restrict__ pool2,
    const float* __restrict__ pooln, const float* __restrict__ a1b,
    const float* __restrict__ a2b, const float* __restrict__ Wbil,
    const float* __restrict__ bbil, float* __restrict__ contr,
    float* __restrict__ tArr1, float* __restrict__ tArr2)
{
  const int tid = threadIdx.x, wv = tid >> 6, j = tid & 63;
  const int bu = blockIdx.x * 4 + wv;
  const float p1 = pool1[(size_t)bu * 64 + j];
  const float p2 = pool2[(size_t)bu * 64 + j];
  const float pn = pooln[(size_t)bu * 64 + j];
  const float A1 = a1b[(size_t)bu * 64 + j];
  const float A2 = a2b[(size_t)bu * 64 + j];
  float v1 = 0.f, v2 = 0.f, vn = 0.f;
  for (int jj = 0; jj < 64; ++jj) {
    const float wr = Wbil[jj * 64 + j];  // coalesced row
    v1 = fmaf(__shfl(p1, jj), wr, v1);
    v2 = fmaf(__shfl(p2, jj), wr, v2);
    vn = fmaf(__shfl(pn, jj), wr, vn);
  }
  const float d11 = waveSum(v1 * A1);
  const float d22 = waveSum(v2 * A2);
  const float dn1 = waveSum(vn * A1);
  const float dn2 = waveSum(vn * A2);
  if (j == 0) {
    const float bb = bbil[0];
    const float z11 = d11 + bb, z22 = d22 + bb, zn1 = dn1 + bb, zn2 = dn2 + bb;
    const float ps1 = 1.f / (1.f + expf(-z11));
    const float ps2 = 1.f / (1.f + expf(-z22));
    const float ns1 = 1.f / (1.f + expf(-zn1));
    const float ns2 = 1.f / (1.f + expf(-zn2));
    contr[bu] = (ns1 - ps1 + 1.f) * 0.5f + (ns2 - ps2 + 1.f) * 0.5f;
    tArr1[bu] = logsig(z11) + logsig(-zn1);
    tArr2[bu] = logsig(z22) + logsig(-zn2);
  }
}

// ---------------- reduction: 4 quantities x BB floats -> accs[0..3] (double) -----
__global__ __launch_bounds__(256) void reduce_kernel(const float* __restrict__ parts,
                                                     double* __restrict__ accs)
{
  __shared__ double sred[4];
  const int t = threadIdx.x, lane = t & 63, wv = t >> 6;
  const float* __restrict__ p = parts + (size_t)blockIdx.x * BB;
  double s = 0.0;
  for (int i = t; i < BB; i += 256) s += (double)p[i];
#pragma unroll
  for (int off = 32; off; off >>= 1) s += __shfl_xor(s, off);
  if (lane == 0) sred[wv] = s;
  __syncthreads();
  if (t == 0) accs[blockIdx.x] = sred[0] + sred[1] + sred[2] + sred[3];
}

__global__ void fin_kernel(const double* __restrict__ acc, float* __restrict__ genw,
                           float* __restrict__ out)
{
  const double T1 = acc[0], T2 = acc[1], S1d = acc[2], S2d = acc[3];
  const double m1 = S1d / (double)BB, m2 = S2d / (double)BB;
  const double Lcon = -(m1 + m2) * 0.25;
  const double Lgen = (T1 + T2) / (2.0 * (double)BB * (double)FINN);
  out[0] = (float)(Lcon + 0.6 * Lgen);
  genw[0] = (float)((sqrt(T1) + sqrt(T2)) / (2.0 * sqrt((double)FINN)));
}

__global__ void score_kernel(const float* __restrict__ contr, const float* __restrict__ genw,
                             float* __restrict__ out)
{
  const int i = blockIdx.x * blockDim.x + threadIdx.x;
  if (i < BB) out[1 + i] = fmaf(0.6f, genw[0], contr[i]);
}

extern "C" void kernel_launch(void* const* d_in, const int* in_sizes, int n_in,
                              void* d_out, int out_size, void* d_ws, size_t ws_size,
                              hipStream_t stream)
{
  const float* feat_p1 = (const float*)d_in[0];
  const float* feat_p2 = (const float*)d_in[1];
  const float* feat_n  = (const float*)d_in[2];
  const float* w_p1 = (const float*)d_in[3];
  const float* w_p2 = (const float*)d_in[4];
  const float* w_n  = (const float*)d_in[5];
  const float* W_enc = (const float*)d_in[6];
  const float* b_enc = (const float*)d_in[7];
  const float* W_dec = (const float*)d_in[8];
  const float* b_dec = (const float*)d_in[9];
  const float* W_bil = (const float*)d_in[10];
  const float* b_bil = (const float*)d_in[11];
  const int* src_p1 = (const int*)d_in[12];
  const int* dst_p1 = (const int*)d_in[13];
  const int* src_p2 = (const int*)d_in[14];
  const int* dst_p2 = (const int*)d_in[15];
  const int* src_n  = (const int*)d_in[16];
  const int* dst_n  = (const int*)d_in[17];
  float* out = (float*)d_out;

  double* accs = (double*)d_ws;                          // [T1,T2,S1,S2]
  float* genw = (float*)((char*)d_ws + 32);
  uint4* wsB = (uint4*)((char*)d_ws + 1024);             // 40960 B W_enc frags
  float* fws = (float*)((char*)d_ws + 49152);
  float* pool1 = fws;
  float* pool2 = pool1 + (size_t)BB * 64;
  float* pooln = pool2 + (size_t)BB * 64;
  float* a1 = pooln + (size_t)BB * 64;
  float* a2 = a1 + (size_t)BB * 64;
  float* g1 = a2 + (size_t)BB * 64;
  float* g2 = g1 + (size_t)BB * 64;
  float* nd01 = g2 + (size_t)BB * 64;
  float* nd02 = nd01 + BB;
  float* contr = nd02 + BB;
  float* parts = contr + BB;              // [dArr1 | dArr2 | tArr1 | tArr2], 4*BB
  float* dArr1 = parts;
  float* dArr2 = parts + BB;
  float* tArr1 = parts + 2 * BB;
  float* tArr2 = parts + 3 * BB;

  hipLaunchKernelGGL(prep_kernel, dim3(10), dim3(256), 0, stream, W_enc, wsB);
  hipLaunchKernelGGL(enc_kernel, dim3(BB / 4), dim3(256), 0, stream,
                     feat_n, w_n, src_n, dst_n, wsB, b_enc, pooln,
                     (float*)nullptr, (float*)nullptr, (float*)nullptr);
  hipLaunchKernelGGL(enc_kernel, dim3(BB / 4), dim3(256), 0, stream,
                     feat_p1, w_p1, src_p1, dst_p1, wsB, b_enc, pool1, a1, g1, nd01);
  hipLaunchKernelGGL(enc_kernel, dim3(BB / 4), dim3(256), 0, stream,
                     feat_p2, w_p2, src_p2, dst_p2, wsB, b_enc, pool2, a2, g2, nd02);
  hipLaunchKernelGGL(dec_kernel, dim3(BB), dim3(256), 0, stream,
                     g1, nd01, W_dec, b_dec, feat_p1, dArr1);
  hipLaunchKernelGGL(dec_kernel, dim3(BB), dim3(256), 0, stream,
                     g2, nd02, W_dec, b_dec, feat_p2, dArr2);
  hipLaunchKernelGGL(bil_kernel, dim3(BB / 4), dim3(256), 0, stream,
                     pool1, pool2, pooln, a1, a2, W_bil, b_bil, contr, tArr1, tArr2);
  hipLaunchKernelGGL(reduce_kernel, dim3(4), dim3(256), 0, stream, parts, accs);
  hipLaunchKernelGGL(fin_kernel, dim3(1), dim3(1), 0, stream, accs, genw, out);
  hipLaunchKernelGGL(score_kernel, dim3((BB + 255) / 256), dim3(256), 0, stream,
                     contr, genw, out);
}